// Round 1
// baseline (25595.158 us; speedup 1.0000x reference)
//
#include <hip/hip_runtime.h>
#include <math.h>

#define NS 64
#define NC 32
#define NMM 96
#define TT 512
#define NB 16

// ---------------- LDS float offsets (backward) ----------------
#define VOFF   0        // V[64][64]
#define FOFF   4096     // F[64][96]  (cols 0..63 = A row, 64..95 = B row)
#define WOFF   10240    // W[64][96]  W = V @ F
#define QHOFF  16384    // Qh[96][100] (col 96 = qh vector)
#define LIOFF  25984    // Linv[32][33]
#define T1OFF  27040    // T1[32][66]
#define KKOFF  29152    // Kk[32][68]  (col 64 = k)
#define SMEMF  31328    // 125312 bytes

// ---------------- LDS float offsets (forward overlay) ----------------
#define AB0OFF 0        // AB[64][98]
#define AB1OFF 6272
#define KFOFF  12544    // Kf[32][65]
#define XOFF   14624    // x[64]
#define UOFF   14688    // u[32]
#define CFOFF  14720    // cF[2][64]

// ---------------- workspace float offsets ----------------
#define WSK_STRIDE 2080                      // per (b,t): K[32][64] + k[32], row j: [j*65 + c], c=64 is k
#define WSV_OFF  ((size_t)NB * TT * WSK_STRIDE)
#define WS_FLOATS (WSV_OFF + (size_t)NB * 64)

__device__ __forceinline__ float lanebc(float x, int lane) {
    return __int_as_float(__builtin_amdgcn_readlane(__float_as_int(x), lane));
}

__launch_bounds__(256, 1)
__global__ void lqr_kernel(const float* __restrict__ Q, const float* __restrict__ P,
                           const float* __restrict__ A, const float* __restrict__ B,
                           const float* __restrict__ c1, const float* __restrict__ xinit,
                           float* __restrict__ out, float* __restrict__ ws)
{
    __shared__ float sm[SMEMF];
    const int tid = threadIdx.x;
    const int b   = blockIdx.x;
    float* wsK = ws;
    float* wsv = ws + WSV_OFF;

    const int ty = tid >> 4;   // 0..15
    const int tx = tid & 15;   // 0..15
    const bool diag = (ty == tx);

    // ---------------- init: V = 0, v = 0, stage F for t=511 ----------------
    for (int q = tid; q < 4096; q += 256) sm[VOFF + q] = 0.0f;
    if (tid < 64) wsv[b * 64 + tid] = 0.0f;
    {
        const size_t bt = (size_t)b * TT + (TT - 1);
#pragma unroll
        for (int it = 0; it < 6; ++it) {
            int q = tid + 256 * it, row = q / 24, g = q % 24;
            const float* src = (g < 16) ? (A + (bt * 64 + row) * 64 + 4 * g)
                                        : (B + (bt * 64 + row) * 32 + 4 * (g - 16));
            *(float4*)&sm[FOFF + row * 96 + 4 * g] = *(const float4*)src;
        }
    }
    __syncthreads();

    // ================= backward Riccati recursion =================
    for (int t = TT - 1; t >= 0; --t) {
        const size_t bt  = (size_t)b * TT + t;
        const int    tp  = (t > 0) ? (t - 1) : 0;
        const size_t btp = (size_t)b * TT + tp;

        // ---- issue global loads early (Q tile -> accumulators, p, next F) ----
        float qacc[6][6];
        {
            const float* Qg = Q + bt * (NMM * NMM);
#pragma unroll
            for (int rr = 0; rr < 6; ++rr) {
                const float* qr = Qg + (6 * ty + rr) * NMM + 6 * tx;
#pragma unroll
                for (int c2 = 0; c2 < 3; ++c2) {
                    float2 v = *(const float2*)(qr + 2 * c2);
                    qacc[rr][2 * c2] = v.x; qacc[rr][2 * c2 + 1] = v.y;
                }
            }
        }
        float preg[6];
        if (diag) {
            const float* pg = P + bt * NMM + 6 * ty;
#pragma unroll
            for (int c2 = 0; c2 < 3; ++c2) {
                float2 v = *(const float2*)(pg + 2 * c2);
                preg[2 * c2] = v.x; preg[2 * c2 + 1] = v.y;
            }
        }
        float4 fpre[6];
#pragma unroll
        for (int it = 0; it < 6; ++it) {
            int q = tid + 256 * it, row = q / 24, g = q % 24;
            const float* src = (g < 16) ? (A + (btp * 64 + row) * 64 + 4 * g)
                                        : (B + (btp * 64 + row) * 32 + 4 * (g - 16));
            fpre[it] = *(const float4*)src;
        }

        // ---- W = V @ F  (64x96, inner 64); thread tile 4x6 ----
        {
            float wacc[4][6];
#pragma unroll
            for (int rr = 0; rr < 4; ++rr)
#pragma unroll
                for (int cc = 0; cc < 6; ++cc) wacc[rr][cc] = 0.0f;
            for (int l0 = 0; l0 < 64; l0 += 4) {
                float4 va[4];
#pragma unroll
                for (int rr = 0; rr < 4; ++rr)
                    va[rr] = *(const float4*)&sm[VOFF + (4 * ty + rr) * 64 + l0];
#pragma unroll
                for (int dl = 0; dl < 4; ++dl) {
                    float fb[6];
#pragma unroll
                    for (int c2 = 0; c2 < 3; ++c2) {
                        float2 v = *(const float2*)&sm[FOFF + (l0 + dl) * 96 + 6 * tx + 2 * c2];
                        fb[2 * c2] = v.x; fb[2 * c2 + 1] = v.y;
                    }
#pragma unroll
                    for (int rr = 0; rr < 4; ++rr) {
                        float vv = (dl == 0) ? va[rr].x : (dl == 1) ? va[rr].y : (dl == 2) ? va[rr].z : va[rr].w;
#pragma unroll
                        for (int cc = 0; cc < 6; ++cc) wacc[rr][cc] += vv * fb[cc];
                    }
                }
            }
#pragma unroll
            for (int rr = 0; rr < 4; ++rr)
#pragma unroll
                for (int c2 = 0; c2 < 3; ++c2)
                    *(float2*)&sm[WOFF + (4 * ty + rr) * 96 + 6 * tx + 2 * c2] =
                        make_float2(wacc[rr][2 * c2], wacc[rr][2 * c2 + 1]);
        }
        __syncthreads();   // B1: W ready

        // ---- Qh = Q + F^T W (96x96, inner 64); thread tile 6x6. qh on diag threads ----
#pragma unroll 2
        for (int i = 0; i < 64; ++i) {
            float fa[6], wb[6];
#pragma unroll
            for (int c2 = 0; c2 < 3; ++c2) {
                float2 v1 = *(const float2*)&sm[FOFF + i * 96 + 6 * ty + 2 * c2];
                fa[2 * c2] = v1.x; fa[2 * c2 + 1] = v1.y;
                float2 v2 = *(const float2*)&sm[WOFF + i * 96 + 6 * tx + 2 * c2];
                wb[2 * c2] = v2.x; wb[2 * c2 + 1] = v2.y;
            }
#pragma unroll
            for (int rr = 0; rr < 6; ++rr)
#pragma unroll
                for (int cc = 0; cc < 6; ++cc) qacc[rr][cc] += fa[rr] * wb[cc];
        }
        float qhreg[6];
        if (diag) {
            const float* cg = c1 + bt * 64;
            const float* vg = wsv + b * 64;
#pragma unroll
            for (int jj = 0; jj < 6; ++jj) qhreg[jj] = preg[jj];
            for (int i = 0; i < 64; ++i) {
                float ci = cg[i], vi = vg[i];
#pragma unroll
                for (int jj = 0; jj < 6; ++jj)
                    qhreg[jj] += sm[WOFF + i * 96 + 6 * ty + jj] * ci
                               + sm[FOFF + i * 96 + 6 * ty + jj] * vi;
            }
        }
        // write Qh (+ qh column 96)
#pragma unroll
        for (int rr = 0; rr < 6; ++rr)
#pragma unroll
            for (int c2 = 0; c2 < 3; ++c2)
                *(float2*)&sm[QHOFF + (6 * ty + rr) * 100 + 6 * tx + 2 * c2] =
                    make_float2(qacc[rr][2 * c2], qacc[rr][2 * c2 + 1]);
        if (diag) {
#pragma unroll
            for (int jj = 0; jj < 6; ++jj) sm[QHOFF + (6 * ty + jj) * 100 + 96] = qhreg[jj];
        }
        __syncthreads();   // B2: Qh ready

        // ---- Cholesky of Quu + explicit L^-1, wave 0 in registers ----
        if (tid < 64) {
            const int i = tid & 31;          // my row (lanes 32..63 mirror)
            float a[32], rinv[32];
#pragma unroll
            for (int j4 = 0; j4 < 8; ++j4) {
                float4 v = *(const float4*)&sm[QHOFF + (64 + i) * 100 + 64 + 4 * j4];
                a[4 * j4] = v.x; a[4 * j4 + 1] = v.y; a[4 * j4 + 2] = v.z; a[4 * j4 + 3] = v.w;
            }
#pragma unroll
            for (int j = 0; j < 32; ++j) {
                float dj = lanebc(a[j], j);
                float rj = rsqrtf(dj);
                rinv[j] = rj;
                a[j] *= rj;                        // L[i][j] for i>=j
#pragma unroll
                for (int k = j + 1; k < 32; ++k)
                    a[k] -= a[j] * lanebc(a[j], k);
            }
            // forward substitution: column i of L^-1
            float y[32];
#pragma unroll
            for (int r = 0; r < 32; ++r) {
                float acc0 = (r == i) ? 1.0f : 0.0f, acc1 = 0.0f;
#pragma unroll
                for (int j = 0; j < r; ++j) {
                    float lrj = lanebc(a[j], r);
                    if (j & 1) acc1 -= lrj * y[j]; else acc0 -= lrj * y[j];
                }
                y[r] = (acc0 + acc1) * rinv[r];
            }
            if (tid < 32) {
#pragma unroll
                for (int r = 0; r < 32; ++r) sm[LIOFF + r * 33 + i] = y[r];
            }
        }
        __syncthreads();   // B3: Linv ready

        // ---- T1 = Linv @ [Qux | qu]  (32 x 65) ----
        {
            const int ti = tid >> 3, cg = tid & 7;
            float t1a[8]; float t1b = 0.0f;
#pragma unroll
            for (int q = 0; q < 8; ++q) t1a[q] = 0.0f;
            for (int j = 0; j < 32; ++j) {
                float lv = sm[LIOFF + ti * 33 + j];
                const float* qrow = &sm[QHOFF + (64 + j) * 100];
#pragma unroll
                for (int q = 0; q < 8; ++q) t1a[q] += lv * qrow[cg + 8 * q];
                t1b += lv * qrow[96];
            }
#pragma unroll
            for (int q = 0; q < 8; ++q) sm[T1OFF + ti * 66 + cg + 8 * q] = t1a[q];
            if (cg == 0) sm[T1OFF + ti * 66 + 64] = t1b;
        }
        __syncthreads();   // B4

        // ---- Kk = -(Linv^T @ T1)  (32 x 65), also store to ws ----
        {
            const int kj = tid >> 3, cg = tid & 7;
            float ka[8]; float kb = 0.0f;
#pragma unroll
            for (int q = 0; q < 8; ++q) ka[q] = 0.0f;
            for (int i2 = 0; i2 < 32; ++i2) {
                float lv = sm[LIOFF + i2 * 33 + kj];
                const float* trow = &sm[T1OFF + i2 * 66];
#pragma unroll
                for (int q = 0; q < 8; ++q) ka[q] += lv * trow[cg + 8 * q];
                kb += lv * trow[64];
            }
            float* wrow = wsK + bt * WSK_STRIDE + kj * 65;
#pragma unroll
            for (int q = 0; q < 8; ++q) {
                float v = -ka[q];
                sm[KKOFF + kj * 68 + cg + 8 * q] = v;
                wrow[cg + 8 * q] = v;
            }
            if (cg == 0) {
                float v = -kb;
                sm[KKOFF + kj * 68 + 64] = v;
                wrow[64] = v;
            }
        }
        __syncthreads();   // B5: Kk ready

        // ---- Vn = Qxx + Qxu K, symmetrize; vn = qx + Qxu k ----
        {
            float vacc[4][4];
#pragma unroll
            for (int rr = 0; rr < 4; ++rr) {
                float4 v = *(const float4*)&sm[QHOFF + (4 * ty + rr) * 100 + 4 * tx];
                vacc[rr][0] = v.x; vacc[rr][1] = v.y; vacc[rr][2] = v.z; vacc[rr][3] = v.w;
            }
            for (int j = 0; j < 32; ++j) {
                float4 kv = *(const float4*)&sm[KKOFF + j * 68 + 4 * tx];
#pragma unroll
                for (int rr = 0; rr < 4; ++rr) {
                    float qv = sm[QHOFF + (4 * ty + rr) * 100 + 64 + j];   // Qxu[r][j] = Qh[r][64+j]
                    vacc[rr][0] += qv * kv.x; vacc[rr][1] += qv * kv.y;
                    vacc[rr][2] += qv * kv.z; vacc[rr][3] += qv * kv.w;
                }
            }
            float vnv = 0.0f;
            if (tid < 64) {
                vnv = sm[QHOFF + tid * 100 + 96];
                for (int j = 0; j < 32; ++j)
                    vnv += sm[QHOFF + tid * 100 + 64 + j] * sm[KKOFF + j * 68 + 64];
            }
            // write raw Vn in place over Qxx slots (own tile only)
#pragma unroll
            for (int rr = 0; rr < 4; ++rr)
                *(float4*)&sm[QHOFF + (4 * ty + rr) * 100 + 4 * tx] =
                    make_float4(vacc[rr][0], vacc[rr][1], vacc[rr][2], vacc[rr][3]);
            __syncthreads();   // B6: raw Vn ready
            // symmetrize into V
#pragma unroll
            for (int rr = 0; rr < 4; ++rr)
#pragma unroll
                for (int cc = 0; cc < 4; ++cc) {
                    float tv = sm[QHOFF + (4 * tx + cc) * 100 + 4 * ty + rr];
                    sm[VOFF + (4 * ty + rr) * 64 + 4 * tx + cc] = 0.5f * (vacc[rr][cc] + tv);
                }
            if (tid < 64) wsv[b * 64 + tid] = vnv;
            // stage next F (prefetched at top of step)
#pragma unroll
            for (int it = 0; it < 6; ++it) {
                int q = tid + 256 * it, row = q / 24, g = q % 24;
                *(float4*)&sm[FOFF + row * 96 + 4 * g] = fpre[it];
            }
        }
        __syncthreads();   // B7: next-step state ready
    }

    // ================= forward rollout =================
    __syncthreads();
    {
        const size_t bt0 = (size_t)b * TT;
#pragma unroll
        for (int it = 0; it < 6; ++it) {
            int q = tid + 256 * it, row = q / 24, g = q % 24;
            const float* src = (g < 16) ? (A + (bt0 * 64 + row) * 64 + 4 * g)
                                        : (B + (bt0 * 64 + row) * 32 + 4 * (g - 16));
            float4 v = *(const float4*)src;
            *(float2*)&sm[AB0OFF + row * 98 + 4 * g]     = make_float2(v.x, v.y);
            *(float2*)&sm[AB0OFF + row * 98 + 4 * g + 2] = make_float2(v.z, v.w);
        }
        if (tid < 130) {
            const float* kg = wsK + bt0 * WSK_STRIDE + tid * 16;
#pragma unroll
            for (int ff = 0; ff < 4; ++ff)
                *(float4*)&sm[KFOFF + tid * 16 + 4 * ff] = *(const float4*)(kg + 4 * ff);
        }
        if (tid < 64) {
            sm[XOFF + tid]  = xinit[b * 64 + tid];
            sm[CFOFF + tid] = c1[bt0 * 64 + tid];
        }
    }
    __syncthreads();

    for (int t = 0; t < TT; ++t) {
        const size_t bt = (size_t)b * TT + t;
        const int cur = t & 1, nxt = cur ^ 1;
        const int tn = (t < TT - 1) ? t + 1 : t;
        const size_t btn = (size_t)b * TT + tn;

        // prefetch next-step A|B, K, c into registers
        float4 abreg[6];
#pragma unroll
        for (int it = 0; it < 6; ++it) {
            int q = tid + 256 * it, row = q / 24, g = q % 24;
            const float* src = (g < 16) ? (A + (btn * 64 + row) * 64 + 4 * g)
                                        : (B + (btn * 64 + row) * 32 + 4 * (g - 16));
            abreg[it] = *(const float4*)src;
        }
        float4 kreg[4];
        if (tid < 130) {
            const float* kg = wsK + btn * WSK_STRIDE + tid * 16;
#pragma unroll
            for (int ff = 0; ff < 4; ++ff) kreg[ff] = *(const float4*)(kg + 4 * ff);
        }
        float creg = (tid < 64) ? c1[btn * 64 + tid] : 0.0f;

        // ---- u = K x + k; write out row t ----
        if (tid < 128) {
            const int ru = tid >> 2, qq = tid & 3;
            float pa = 0.0f;
            const float* kr = &sm[KFOFF + ru * 65 + 16 * qq];
            const float* xr = &sm[XOFF + 16 * qq];
#pragma unroll
            for (int l = 0; l < 16; ++l) pa += kr[l] * xr[l];
            pa += __shfl_xor(pa, 1);
            pa += __shfl_xor(pa, 2);
            if (qq == 0) {
                float u = pa + sm[KFOFF + ru * 65 + 64];
                sm[UOFF + ru] = u;
                out[bt * 96 + 64 + ru] = u;
            }
        } else if (tid < 192) {
            int r = tid - 128;
            out[bt * 96 + r] = sm[XOFF + r];
        }
        __syncthreads();

        // ---- xn = A x + B u + c ----
        float xn = 0.0f;
        if (tid < 128) {
            const int r = tid >> 1, h = tid & 1;
            const float* ar = &sm[(cur ? AB1OFF : AB0OFF) + r * 98];
            float pa = 0.0f;
            if (h == 0) {
#pragma unroll
                for (int l = 0; l < 48; ++l) pa += ar[l] * sm[XOFF + l];
            } else {
#pragma unroll
                for (int l = 48; l < 64; ++l) pa += ar[l] * sm[XOFF + l];
#pragma unroll
                for (int l = 64; l < 96; ++l) pa += ar[l] * sm[UOFF + l - 64];
            }
            pa += __shfl_xor(pa, 1);
            xn = pa + sm[CFOFF + cur * 64 + r];
        }
        __syncthreads();

        // commit x, stage next-step buffers
        if (tid < 128 && (tid & 1) == 0) sm[XOFF + (tid >> 1)] = xn;
        {
            const int abn = nxt ? AB1OFF : AB0OFF;
#pragma unroll
            for (int it = 0; it < 6; ++it) {
                int q = tid + 256 * it, row = q / 24, g = q % 24;
                float4 v = abreg[it];
                *(float2*)&sm[abn + row * 98 + 4 * g]     = make_float2(v.x, v.y);
                *(float2*)&sm[abn + row * 98 + 4 * g + 2] = make_float2(v.z, v.w);
            }
            if (tid < 130) {
#pragma unroll
                for (int ff = 0; ff < 4; ++ff)
                    *(float4*)&sm[KFOFF + tid * 16 + 4 * ff] = kreg[ff];
            }
            if (tid < 64) sm[CFOFF + nxt * 64 + tid] = creg;
        }
        __syncthreads();
    }
}

extern "C" void kernel_launch(void* const* d_in, const int* in_sizes, int n_in,
                              void* d_out, int out_size, void* d_ws, size_t ws_size,
                              hipStream_t stream) {
    (void)in_sizes; (void)n_in; (void)out_size;
    const float* Q  = (const float*)d_in[0];
    const float* p  = (const float*)d_in[1];
    const float* A  = (const float*)d_in[2];
    const float* B  = (const float*)d_in[3];
    const float* c1 = (const float*)d_in[4];
    const float* xi = (const float*)d_in[5];
    if (ws_size < WS_FLOATS * sizeof(float)) return;   // fail loudly (output stays poisoned)
    lqr_kernel<<<NB, 256, 0, stream>>>(Q, p, A, B, c1, xi, (float*)d_out, (float*)d_ws);
}

// Round 2
// 14730.356 us; speedup vs baseline: 1.7376x; 1.7376x over previous
//
#include <hip/hip_runtime.h>
#include <math.h>

#define TT 512
#define NB 16

// ---------------- LDS float offsets (backward) ----------------
#define VOF 0        // V[64][68]
#define FTO 4352     // FT[96][68]   FT[c][k] = F[k][c]
#define WTO 10880    // WT[96][68]   WT[c][i] = W[i][c]
#define KTO 10880    // KT[64][36]   (aliases WT; live only B5..B6)
#define QHO 17408    // QH[96][100]  (col 96 = qh)
#define LIO 27008    // LI[32][36]
#define T1O 28160    // T1[32][68]   (col 64 = qu-solve)
#define VVO 30336    // v[64]
#define CVO 30400    // c[64]
#define KVO 30464    // k[32]
#define SMF 30496    // 121,984 bytes

// ---------------- LDS float offsets (forward overlay) ----------------
#define AB0 0        // AB[64][100] (cols 0..63 A, 64..95 B)
#define AB1 6400
#define KF0 12800    // KF[32][68]  (col 64 = k)
#define KF1 14976
#define XB0 17152    // x[64]
#define XB1 17216
#define UBO 17280    // u[32]
#define AXO 17312    // ax[64]

#define WSK_STRIDE 2080   // per (b,t): rows j: [j*65 + c], col 64 = k

__device__ __forceinline__ float lanebc(float x, int lane) {
    return __int_as_float(__builtin_amdgcn_readlane(__float_as_int(x), lane));
}
__device__ __forceinline__ float dot4(float4 a, float4 b) {
    return a.x * b.x + a.y * b.y + a.z * b.z + a.w * b.w;
}

__launch_bounds__(512, 2)
__global__ void lqr_kernel(const float* __restrict__ Q, const float* __restrict__ P,
                           const float* __restrict__ A, const float* __restrict__ B,
                           const float* __restrict__ c1, const float* __restrict__ xinit,
                           float* __restrict__ out, float* __restrict__ ws)
{
    __shared__ float sm[SMF];
    const int tid = threadIdx.x;
    const int b   = blockIdx.x;
    float* wsK = ws;

    // ---------------- init: V = 0, v = 0, stage FT for t=511 ----------------
    for (int q = tid; q < 4352; q += 512) sm[VOF + q] = 0.0f;
    if (tid < 64) sm[VVO + tid] = 0.0f;
    {
        const size_t bt = (size_t)b * TT + (TT - 1);
#pragma unroll
        for (int it = 0; it < 3; ++it) {
            int q = tid + 512 * it, row = q / 24, g = q % 24;
            const float* src = (g < 16) ? (A + (bt * 64 + row) * 64 + 4 * g)
                                        : (B + (bt * 64 + row) * 32 + 4 * (g - 16));
            float4 v = *(const float4*)src;
            sm[FTO + (4 * g + 0) * 68 + row] = v.x;
            sm[FTO + (4 * g + 1) * 68 + row] = v.y;
            sm[FTO + (4 * g + 2) * 68 + row] = v.z;
            sm[FTO + (4 * g + 3) * 68 + row] = v.w;
        }
    }
    __syncthreads();

    const int ig  = tid >> 5;   // 0..15 (GEMM1 row group, GEMM2 row group)
    const int cg  = tid & 31;   // 0..31 (col group)

    // ================= backward Riccati recursion =================
    for (int t = TT - 1; t >= 0; --t) {
        const size_t bt  = (size_t)b * TT + t;
        const size_t btp = (size_t)b * TT + ((t > 0) ? (t - 1) : 0);

        // ---- prefetch (global -> regs), issued before GEMM1 ----
        float qpre[6][3];
        {
            const float* Qg = Q + bt * 9216;
#pragma unroll
            for (int rr = 0; rr < 6; ++rr)
#pragma unroll
                for (int cc = 0; cc < 3; ++cc)
                    qpre[rr][cc] = Qg[(6 * ig + rr) * 96 + 3 * cg + cc];
        }
        float4 fpre[6];
        if (tid < 256) {
#pragma unroll
            for (int it = 0; it < 6; ++it) {
                int q = tid + 256 * it, row = q / 24, g = q % 24;
                const float* src = (g < 16) ? (A + (btp * 64 + row) * 64 + 4 * g)
                                            : (B + (btp * 64 + row) * 32 + 4 * (g - 16));
                fpre[it] = *(const float4*)src;
            }
        }
        float pp0 = 0.0f, pp1 = 0.0f;
        if (tid >= 64 && tid < 128) {
            int L = tid - 64;
            pp0 = P[bt * 96 + L];
            if (L < 32) pp1 = P[bt * 96 + 64 + L];
            sm[CVO + L] = c1[bt * 64 + L];
        }

        // ---- GEMM1: WT[c][i] = sum_k V[i][k] F[k][c] ----
        {
            float wa[4][3];
#pragma unroll
            for (int rr = 0; rr < 4; ++rr)
#pragma unroll
                for (int cc = 0; cc < 3; ++cc) wa[rr][cc] = 0.0f;
#pragma unroll 4
            for (int k4 = 0; k4 < 16; ++k4) {
                float4 va[4], fb[3];
#pragma unroll
                for (int rr = 0; rr < 4; ++rr)
                    va[rr] = *(const float4*)&sm[VOF + (4 * ig + rr) * 68 + 4 * k4];
#pragma unroll
                for (int cc = 0; cc < 3; ++cc)
                    fb[cc] = *(const float4*)&sm[FTO + (3 * cg + cc) * 68 + 4 * k4];
#pragma unroll
                for (int rr = 0; rr < 4; ++rr)
#pragma unroll
                    for (int cc = 0; cc < 3; ++cc) wa[rr][cc] += dot4(va[rr], fb[cc]);
            }
#pragma unroll
            for (int cc = 0; cc < 3; ++cc)
                *(float4*)&sm[WTO + (3 * cg + cc) * 68 + 4 * ig] =
                    make_float4(wa[0][cc], wa[1][cc], wa[2][cc], wa[3][cc]);
        }
        __syncthreads();   // B1: WT ready

        // ---- GEMM2: QH[r][c] = Q + sum_i FT[r][i] WT[c][i] ----
        {
            float qa[6][3];
#pragma unroll
            for (int rr = 0; rr < 6; ++rr)
#pragma unroll
                for (int cc = 0; cc < 3; ++cc) qa[rr][cc] = 0.0f;
#pragma unroll 2
            for (int i4 = 0; i4 < 16; ++i4) {
                float4 fa[6], wb[3];
#pragma unroll
                for (int rr = 0; rr < 6; ++rr)
                    fa[rr] = *(const float4*)&sm[FTO + (6 * ig + rr) * 68 + 4 * i4];
#pragma unroll
                for (int cc = 0; cc < 3; ++cc)
                    wb[cc] = *(const float4*)&sm[WTO + (3 * cg + cc) * 68 + 4 * i4];
#pragma unroll
                for (int rr = 0; rr < 6; ++rr)
#pragma unroll
                    for (int cc = 0; cc < 3; ++cc) qa[rr][cc] += dot4(fa[rr], wb[cc]);
            }
#pragma unroll
            for (int rr = 0; rr < 6; ++rr)
#pragma unroll
                for (int cc = 0; cc < 3; ++cc)
                    sm[QHO + (6 * ig + rr) * 100 + 3 * cg + cc] = qa[rr][cc] + qpre[rr][cc];
        }
        __syncthreads();   // B2: QH ready

        // ---- wave0: Cholesky(Quu) + explicit L^-1 ; wave1: qh vector ----
        if (tid < 64) {
            const int i = tid & 31;
            float a[32], rinv[32];
#pragma unroll
            for (int j4 = 0; j4 < 8; ++j4) {
                float4 v = *(const float4*)&sm[QHO + (64 + i) * 100 + 64 + 4 * j4];
                a[4 * j4] = v.x; a[4 * j4 + 1] = v.y; a[4 * j4 + 2] = v.z; a[4 * j4 + 3] = v.w;
            }
#pragma unroll
            for (int j = 0; j < 32; ++j) {
                float dj = lanebc(a[j], j);
                float rj = rsqrtf(dj);
                rinv[j] = rj;
                a[j] *= rj;
#pragma unroll
                for (int k = j + 1; k < 32; ++k)
                    a[k] -= a[j] * lanebc(a[j], k);
            }
            float y[32];
#pragma unroll
            for (int r = 0; r < 32; ++r) {
                float acc0 = (r == i) ? 1.0f : 0.0f, acc1 = 0.0f;
#pragma unroll
                for (int j = 0; j < r; ++j) {
                    float lrj = lanebc(a[j], r);
                    if (j & 1) acc1 -= lrj * y[j]; else acc0 -= lrj * y[j];
                }
                y[r] = (acc0 + acc1) * rinv[r];
            }
            if (tid < 32) {
#pragma unroll
                for (int r = 0; r < 32; ++r) sm[LIO + r * 36 + i] = y[r];
            }
        } else if (tid < 128) {
            // qh[j] = p[j] + sum_i ( W[i][j] c[i] + F[i][j] v[i] )
            const int L = tid - 64;
            float acc0 = pp0, acc1 = pp1;
#pragma unroll 4
            for (int i4 = 0; i4 < 16; ++i4) {
                float4 c4 = *(const float4*)&sm[CVO + 4 * i4];
                float4 v4 = *(const float4*)&sm[VVO + 4 * i4];
                float4 w0 = *(const float4*)&sm[WTO + L * 68 + 4 * i4];
                float4 f0 = *(const float4*)&sm[FTO + L * 68 + 4 * i4];
                acc0 += dot4(w0, c4) + dot4(f0, v4);
                if (L < 32) {
                    float4 w1 = *(const float4*)&sm[WTO + (64 + L) * 68 + 4 * i4];
                    float4 f1 = *(const float4*)&sm[FTO + (64 + L) * 68 + 4 * i4];
                    acc1 += dot4(w1, c4) + dot4(f1, v4);
                }
            }
            sm[QHO + L * 100 + 96] = acc0;
            if (L < 32) sm[QHO + (64 + L) * 100 + 96] = acc1;
        }
        __syncthreads();   // B3: LI + qh ready

        // ---- waves 4-7: T1 = Linv @ [Qux | qu] ; waves 0-3: stage next FT ----
        if (tid >= 256) {
            const int ti = (tid - 256) >> 3, cq = tid & 7;
            float acc[8], accq = 0.0f;
#pragma unroll
            for (int q = 0; q < 8; ++q) acc[q] = 0.0f;
#pragma unroll 2
            for (int j4 = 0; j4 < 8; ++j4) {
                float4 lv = *(const float4*)&sm[LIO + ti * 36 + 4 * j4];
#pragma unroll
                for (int dj = 0; dj < 4; ++dj) {
                    int j = 4 * j4 + dj;
                    float l = (dj == 0) ? lv.x : (dj == 1) ? lv.y : (dj == 2) ? lv.z : lv.w;
                    float4 q0 = *(const float4*)&sm[QHO + (64 + j) * 100 + 8 * cq];
                    float4 q1 = *(const float4*)&sm[QHO + (64 + j) * 100 + 8 * cq + 4];
                    acc[0] += l * q0.x; acc[1] += l * q0.y; acc[2] += l * q0.z; acc[3] += l * q0.w;
                    acc[4] += l * q1.x; acc[5] += l * q1.y; acc[6] += l * q1.z; acc[7] += l * q1.w;
                    accq += l * sm[QHO + (64 + j) * 100 + 96];
                }
            }
            *(float4*)&sm[T1O + ti * 68 + 8 * cq]     = make_float4(acc[0], acc[1], acc[2], acc[3]);
            *(float4*)&sm[T1O + ti * 68 + 8 * cq + 4] = make_float4(acc[4], acc[5], acc[6], acc[7]);
            if (cq == 7) sm[T1O + ti * 68 + 64] = accq;
        } else {
#pragma unroll
            for (int it = 0; it < 6; ++it) {
                int q = tid + 256 * it, row = q / 24, g = q % 24;
                float4 v = fpre[it];
                sm[FTO + (4 * g + 0) * 68 + row] = v.x;
                sm[FTO + (4 * g + 1) * 68 + row] = v.y;
                sm[FTO + (4 * g + 2) * 68 + row] = v.z;
                sm[FTO + (4 * g + 3) * 68 + row] = v.w;
            }
        }
        __syncthreads();   // B4: T1 + next FT ready

        // ---- waves 0-3: KT = -(Linv^T T1) + ws ; wave 4: kvec ----
        if (tid < 256) {
            const int c = tid >> 2, jg = tid & 3;
            float acc[8];
#pragma unroll
            for (int q = 0; q < 8; ++q) acc[q] = 0.0f;
#pragma unroll 4
            for (int i = 0; i < 32; ++i) {
                float tv = sm[T1O + i * 68 + c];
                float4 l0 = *(const float4*)&sm[LIO + i * 36 + 8 * jg];
                float4 l1 = *(const float4*)&sm[LIO + i * 36 + 8 * jg + 4];
                acc[0] += tv * l0.x; acc[1] += tv * l0.y; acc[2] += tv * l0.z; acc[3] += tv * l0.w;
                acc[4] += tv * l1.x; acc[5] += tv * l1.y; acc[6] += tv * l1.z; acc[7] += tv * l1.w;
            }
            *(float4*)&sm[KTO + c * 36 + 8 * jg]     = make_float4(-acc[0], -acc[1], -acc[2], -acc[3]);
            *(float4*)&sm[KTO + c * 36 + 8 * jg + 4] = make_float4(-acc[4], -acc[5], -acc[6], -acc[7]);
            float* wrow = wsK + bt * WSK_STRIDE;
#pragma unroll
            for (int jj = 0; jj < 8; ++jj)
                wrow[(8 * jg + jj) * 65 + c] = -acc[jj];
        } else if (tid < 288) {
            const int j = tid & 31;
            float acc = 0.0f;
#pragma unroll 4
            for (int i = 0; i < 32; ++i)
                acc += sm[LIO + i * 36 + j] * sm[T1O + i * 68 + 64];
            sm[KVO + j] = -acc;
            wsK[bt * WSK_STRIDE + j * 65 + 64] = -acc;
        }
        __syncthreads();   // B5: KT + kvec ready

        // ---- waves 0-3: Vn = sym(Qxx + Qxu K) -> V (tile-pair) ; wave6: vn ----
        if (tid < 256) {
            const int rg = tid >> 4, cgv = tid & 15;
            if (rg >= cgv) {
                float accA[4][4], accB[4][4];
#pragma unroll
                for (int rr = 0; rr < 4; ++rr) {
                    float4 v = *(const float4*)&sm[QHO + (4 * rg + rr) * 100 + 4 * cgv];
                    accA[rr][0] = v.x; accA[rr][1] = v.y; accA[rr][2] = v.z; accA[rr][3] = v.w;
                    float4 u = *(const float4*)&sm[QHO + (4 * cgv + rr) * 100 + 4 * rg];
                    accB[rr][0] = u.x; accB[rr][1] = u.y; accB[rr][2] = u.z; accB[rr][3] = u.w;
                }
#pragma unroll 2
                for (int k4 = 0; k4 < 8; ++k4) {
                    float4 qa[4], qb[4], ka[4], kb[4];
#pragma unroll
                    for (int rr = 0; rr < 4; ++rr) {
                        qa[rr] = *(const float4*)&sm[QHO + (4 * rg + rr) * 100 + 64 + 4 * k4];
                        qb[rr] = *(const float4*)&sm[QHO + (4 * cgv + rr) * 100 + 64 + 4 * k4];
                        ka[rr] = *(const float4*)&sm[KTO + (4 * cgv + rr) * 36 + 4 * k4];
                        kb[rr] = *(const float4*)&sm[KTO + (4 * rg + rr) * 36 + 4 * k4];
                    }
#pragma unroll
                    for (int rr = 0; rr < 4; ++rr)
#pragma unroll
                        for (int cc = 0; cc < 4; ++cc) {
                            accA[rr][cc] += dot4(qa[rr], ka[cc]);
                            accB[rr][cc] += dot4(qb[rr], kb[cc]);
                        }
                }
#pragma unroll
                for (int rr = 0; rr < 4; ++rr) {
                    float4 v0 = make_float4(0.5f * (accA[rr][0] + accB[0][rr]),
                                            0.5f * (accA[rr][1] + accB[1][rr]),
                                            0.5f * (accA[rr][2] + accB[2][rr]),
                                            0.5f * (accA[rr][3] + accB[3][rr]));
                    *(float4*)&sm[VOF + (4 * rg + rr) * 68 + 4 * cgv] = v0;
                    float4 v1 = make_float4(0.5f * (accB[rr][0] + accA[0][rr]),
                                            0.5f * (accB[rr][1] + accA[1][rr]),
                                            0.5f * (accB[rr][2] + accA[2][rr]),
                                            0.5f * (accB[rr][3] + accA[3][rr]));
                    *(float4*)&sm[VOF + (4 * cgv + rr) * 68 + 4 * rg] = v1;
                }
            }
        } else if (tid >= 384 && tid < 448) {
            const int r = tid - 384;
            float acc = sm[QHO + r * 100 + 96];
#pragma unroll 4
            for (int j = 0; j < 32; ++j)
                acc += sm[QHO + r * 100 + 64 + j] * sm[KVO + j];
            sm[VVO + r] = acc;
        }
        __syncthreads();   // B6: V, v ready for next step
    }

    // ================= forward rollout =================
    {
        const size_t bt0 = (size_t)b * TT;
#pragma unroll
        for (int it = 0; it < 3; ++it) {
            int q = tid + 512 * it, row = q / 24, g = q % 24;
            const float* src = (g < 16) ? (A + (bt0 * 64 + row) * 64 + 4 * g)
                                        : (B + (bt0 * 64 + row) * 32 + 4 * (g - 16));
            *(float4*)&sm[AB0 + row * 100 + 4 * g] = *(const float4*)src;
        }
#pragma unroll
        for (int i = 0; i < 5; ++i) {
            int idx = tid + 512 * i;
            if (idx < 2080) {
                int j = idx / 65, c = idx - 65 * j;
                sm[KF0 + j * 68 + c] = wsK[bt0 * WSK_STRIDE + idx];
            }
        }
        if (tid < 64) sm[XB0 + tid] = xinit[b * 64 + tid];
    }
    __syncthreads();

    for (int t = 0; t < TT; ++t) {
        const size_t bt  = (size_t)b * TT + t;
        const size_t btn = (size_t)b * TT + ((t < TT - 1) ? (t + 1) : t);
        const int cur = t & 1;
        const int abC = cur ? AB1 : AB0, abN = cur ? AB0 : AB1;
        const int kfC = cur ? KF1 : KF0, kfN = cur ? KF0 : KF1;
        const int xbC = cur ? XB1 : XB0, xbN = cur ? XB0 : XB1;

        // prefetch next-step AB, K (waves 4-7) ; c1 for ax
        float4 abpre[6];
        float kpre[9];
        float cpre = 0.0f;
        if (tid >= 256) {
            const int t2 = tid - 256;
#pragma unroll
            for (int it = 0; it < 6; ++it) {
                int q = t2 + 256 * it, row = q / 24, g = q % 24;
                const float* src = (g < 16) ? (A + (btn * 64 + row) * 64 + 4 * g)
                                            : (B + (btn * 64 + row) * 32 + 4 * (g - 16));
                abpre[it] = *(const float4*)src;
            }
#pragma unroll
            for (int i = 0; i < 9; ++i) {
                int idx = t2 + 256 * i;
                kpre[i] = (idx < 2080) ? wsK[btn * WSK_STRIDE + idx] : 0.0f;
            }
            cpre = c1[bt * 64 + ((tid - 256) >> 2)];
        }

        // ---- phase A: waves 0-3: u = Kx + k ; waves 4-7: ax = Ax + c, emit x ----
        if (tid < 256) {
            const int j = tid >> 3, q = tid & 7;
            float4 k0 = *(const float4*)&sm[kfC + j * 68 + 8 * q];
            float4 k1 = *(const float4*)&sm[kfC + j * 68 + 8 * q + 4];
            float4 x0 = *(const float4*)&sm[xbC + 8 * q];
            float4 x1 = *(const float4*)&sm[xbC + 8 * q + 4];
            float pa = dot4(k0, x0) + dot4(k1, x1);
            pa += __shfl_xor(pa, 1);
            pa += __shfl_xor(pa, 2);
            pa += __shfl_xor(pa, 4);
            if (q == 0) {
                float u = pa + sm[kfC + j * 68 + 64];
                sm[UBO + j] = u;
                out[bt * 96 + 64 + j] = u;
            }
        } else {
            const int r = (tid - 256) >> 2, q = tid & 3;
            float pa = 0.0f;
#pragma unroll
            for (int e4 = 0; e4 < 4; ++e4) {
                float4 av = *(const float4*)&sm[abC + r * 100 + 16 * q + 4 * e4];
                float4 xv = *(const float4*)&sm[xbC + 16 * q + 4 * e4];
                pa += dot4(av, xv);
            }
            pa += __shfl_xor(pa, 1);
            pa += __shfl_xor(pa, 2);
            if (q == 0) sm[AXO + r] = pa + cpre;
            if (q == 1) out[bt * 96 + r] = sm[xbC + r];
        }
        __syncthreads();

        // ---- phase B: waves 0-3: xn = ax + B u ; waves 4-7: stage next ----
        if (tid < 256) {
            const int r = tid >> 2, q = tid & 3;
            float4 b0 = *(const float4*)&sm[abC + r * 100 + 64 + 8 * q];
            float4 b1 = *(const float4*)&sm[abC + r * 100 + 64 + 8 * q + 4];
            float4 u0 = *(const float4*)&sm[UBO + 8 * q];
            float4 u1 = *(const float4*)&sm[UBO + 8 * q + 4];
            float pa = dot4(b0, u0) + dot4(b1, u1);
            pa += __shfl_xor(pa, 1);
            pa += __shfl_xor(pa, 2);
            if (q == 0) sm[xbN + r] = sm[AXO + r] + pa;
        } else {
            const int t2 = tid - 256;
#pragma unroll
            for (int it = 0; it < 6; ++it) {
                int q = t2 + 256 * it, row = q / 24, g = q % 24;
                *(float4*)&sm[abN + row * 100 + 4 * g] = abpre[it];
            }
#pragma unroll
            for (int i = 0; i < 9; ++i) {
                int idx = t2 + 256 * i;
                if (idx < 2080) {
                    int j = idx / 65, c = idx - 65 * j;
                    sm[kfN + j * 68 + c] = kpre[i];
                }
            }
        }
        __syncthreads();
    }
}

extern "C" void kernel_launch(void* const* d_in, const int* in_sizes, int n_in,
                              void* d_out, int out_size, void* d_ws, size_t ws_size,
                              hipStream_t stream) {
    (void)in_sizes; (void)n_in; (void)out_size;
    const float* Q  = (const float*)d_in[0];
    const float* p  = (const float*)d_in[1];
    const float* A  = (const float*)d_in[2];
    const float* B  = (const float*)d_in[3];
    const float* c1 = (const float*)d_in[4];
    const float* xi = (const float*)d_in[5];
    if (ws_size < (size_t)NB * TT * WSK_STRIDE * sizeof(float)) return;
    lqr_kernel<<<NB, 512, 0, stream>>>(Q, p, A, B, c1, xi, (float*)d_out, (float*)d_ws);
}

// Round 3
// 10672.931 us; speedup vs baseline: 2.3981x; 1.3802x over previous
//
#include <hip/hip_runtime.h>
#include <math.h>

#define TT 512
#define NB 16

// ---------------- LDS byte offsets (backward) ----------------
#define QH_B   0        // QH  [96][100] f32 (col 96 = qh)
#define LI_B   38400    // LI  [32][36]  f32
#define T1_B   43008    // T1T [65][36]  f32  (row 64 = qu-solve)
#define VBH_B  52368    // Vbf-hi [64][72] us
#define VBL_B  61584    // Vbf-lo
#define FTH_B  70800    // FTbf-hi [96][72] us   FT[c][k] = F[k][c]
#define FTL_B  84624
#define WTH_B  98448    // WTbf-hi [96][72] us   WT[c][i] = W[i][c]
#define WTL_B  112272
#define VR_B   98448    // VRAW [64][72] f32 (aliases WT region, P6 only)
#define XUH_B  126096   // QXUbf-hi [64][40] us
#define XUL_B  131216
#define KTH_B  136336   // KTbf-hi [64][40] us   KT[c][j] = K[j][c]
#define KTL_B  141456
#define QHF_B  146576   // qhF [96] f32
#define VV_B   146960   // v [64] f32
#define CV_B   147216   // c [64] f32
#define KV_B   147472   // k [32] f32
#define SMB    147600

// ---------------- forward overlay (float offsets) ----------------
#define AB0 0
#define AB1 6400
#define KF0 12800
#define KF1 14976
#define XB0 17152
#define XB1 17216
#define UBO 17280
#define AXO 17312

#define WSK_STRIDE 2080   // per (b,t): rows j: [j*65 + c], col 64 = k

typedef __attribute__((ext_vector_type(8))) short s8v;
typedef __attribute__((ext_vector_type(4))) float f4v;

__device__ __forceinline__ float lanebc(float x, int lane) {
    return __int_as_float(__builtin_amdgcn_readlane(__float_as_int(x), lane));
}
__device__ __forceinline__ float dot4(float4 a, float4 b) {
    return a.x * b.x + a.y * b.y + a.z * b.z + a.w * b.w;
}
__device__ __forceinline__ unsigned short f2bf(float x) {
    unsigned int u = __float_as_uint(x);
    u += 0x7FFFu + ((u >> 16) & 1u);           // RNE
    return (unsigned short)(u >> 16);
}
__device__ __forceinline__ float bf2f(unsigned short h) {
    return __uint_as_float(((unsigned int)h) << 16);
}
#define MFMA(a,b,c) __builtin_amdgcn_mfma_f32_16x16x32_bf16((a),(b),(c),0,0,0)

__launch_bounds__(512, 2)
__global__ void lqr_kernel(const float* __restrict__ Q, const float* __restrict__ P,
                           const float* __restrict__ A, const float* __restrict__ B,
                           const float* __restrict__ c1, const float* __restrict__ xinit,
                           float* __restrict__ out, float* __restrict__ ws)
{
    __shared__ __align__(16) unsigned char smb[SMB];
    float*          QHf = (float*)(smb + QH_B);
    float*          LIf = (float*)(smb + LI_B);
    float*          T1f = (float*)(smb + T1_B);
    unsigned short* VBH = (unsigned short*)(smb + VBH_B);
    unsigned short* VBL = (unsigned short*)(smb + VBL_B);
    unsigned short* FTH = (unsigned short*)(smb + FTH_B);
    unsigned short* FTL = (unsigned short*)(smb + FTL_B);
    unsigned short* WTH = (unsigned short*)(smb + WTH_B);
    unsigned short* WTL = (unsigned short*)(smb + WTL_B);
    float*          VRW = (float*)(smb + VR_B);
    unsigned short* XUH = (unsigned short*)(smb + XUH_B);
    unsigned short* XUL = (unsigned short*)(smb + XUL_B);
    unsigned short* KTH = (unsigned short*)(smb + KTH_B);
    unsigned short* KTL = (unsigned short*)(smb + KTL_B);
    float*          QHF = (float*)(smb + QHF_B);
    float*          VVf = (float*)(smb + VV_B);
    float*          CVf = (float*)(smb + CV_B);
    float*          KVf = (float*)(smb + KV_B);

    const int tid = threadIdx.x;
    const int b   = blockIdx.x;
    const int wv  = tid >> 6;
    const int ln  = tid & 63;
    const int l15 = ln & 15;
    const int lq  = ln >> 4;
    float* wsK = ws;

    // ---------------- init: Vbf=0, v=0, stage FTbf for t=511 ----------------
    if (tid < 384) {
        const size_t bt = (size_t)b * TT + (TT - 1);
        const int kk = tid & 63, cq = tid >> 6;
#pragma unroll
        for (int q = 0; q < 4; ++q) {
            const float* src = (cq < 4) ? (A + (bt * 64 + kk) * 64 + 16 * cq + 4 * q)
                                        : (B + (bt * 64 + kk) * 32 + 16 * (cq - 4) + 4 * q);
            float4 v = *(const float4*)src;
#pragma unroll
            for (int e = 0; e < 4; ++e) {
                int col = 16 * cq + 4 * q + e;
                float x = (e == 0) ? v.x : (e == 1) ? v.y : (e == 2) ? v.z : v.w;
                unsigned short h = f2bf(x);
                FTH[col * 72 + kk] = h;
                FTL[col * 72 + kk] = f2bf(x - bf2f(h));
            }
        }
    } else {
        float* vb = (float*)VBH;   // zero Vbf hi+lo (4608 floats contiguous)
        for (int i = tid - 384; i < 4608; i += 128) vb[i] = 0.0f;
        if (tid >= 448) VVf[tid - 448] = 0.0f;
    }
    __syncthreads();

    // ================= backward Riccati recursion =================
    for (int t = TT - 1; t >= 0; --t) {
        const size_t bt  = (size_t)b * TT + t;
        const size_t btp = (size_t)b * TT + ((t > 0) ? (t - 1) : 0);

        // ---- P1-top: prefetches ----
        const int g2base = (wv < 4) ? 5 * wv : 20 + 4 * (wv - 4);
        const int g2cnt  = (wv < 4) ? 5 : 4;
        float qpre[5][4];
        {
            const float* Qg = Q + bt * 9216;
            for (int ti = 0; ti < g2cnt; ++ti) {
                int T = g2base + ti, mt = T / 6, nt = T % 6;
#pragma unroll
                for (int rr = 0; rr < 4; ++rr)
                    qpre[ti][rr] = Qg[(16 * mt + 4 * lq + rr) * 96 + 16 * nt + l15];
            }
        }
        float4 fp4[4];
        if (wv >= 1 && wv <= 6) {
            const int tau = tid - 64, kk = tau & 63, cq = tau >> 6;
#pragma unroll
            for (int q = 0; q < 4; ++q) {
                const float* src = (cq < 4) ? (A + (btp * 64 + kk) * 64 + 16 * cq + 4 * q)
                                            : (B + (btp * 64 + kk) * 32 + 16 * (cq - 4) + 4 * q);
                fp4[q] = *(const float4*)src;
            }
        }
        if (wv == 7 && ln < 16)
            *(float4*)&CVf[4 * ln] = *(const float4*)&c1[bt * 64 + 4 * ln];
        float pv = 0.0f;
        if (ln < 48 && (ln & 3) == 0) pv = P[bt * 96 + 12 * wv + (ln >> 2)];

        // ---- P1: GEMM1 (WT = (VF)^T via MFMA) + qhF = p + F^T v ----
        {
#pragma unroll
            for (int tt = 0; tt < 3; ++tt) {
                int T = wv * 3 + tt, mt = T >> 2, nt = T & 3;
                const unsigned short* ah = FTH + (16 * mt + l15) * 72 + 8 * lq;
                const unsigned short* al = FTL + (16 * mt + l15) * 72 + 8 * lq;
                const unsigned short* bh = VBH + (16 * nt + l15) * 72 + 8 * lq;
                const unsigned short* bl = VBL + (16 * nt + l15) * 72 + 8 * lq;
                f4v d = {0.0f, 0.0f, 0.0f, 0.0f};
#pragma unroll
                for (int kc = 0; kc < 2; ++kc) {
                    s8v Ah = *(const s8v*)(ah + 32 * kc);
                    s8v Al = *(const s8v*)(al + 32 * kc);
                    s8v Bh = *(const s8v*)(bh + 32 * kc);
                    s8v Bl = *(const s8v*)(bl + 32 * kc);
                    d = MFMA(Ah, Bh, d);
                    d = MFMA(Ah, Bl, d);
                    d = MFMA(Al, Bh, d);
                }
                int orow = 16 * mt + 4 * lq, ocol = 16 * nt + l15;
#pragma unroll
                for (int rr = 0; rr < 4; ++rr) {
                    float x = d[rr];
                    unsigned short h = f2bf(x);
                    WTH[(orow + rr) * 72 + ocol] = h;
                    WTL[(orow + rr) * 72 + ocol] = f2bf(x - bf2f(h));
                }
            }
            // qhF: row = 12*wv + (ln>>2), k-quarter = ln&3
            if (ln < 48) {
                int row = 12 * wv + (ln >> 2), kq = ln & 3;
                float acc = 0.0f;
                const unsigned short* fh = FTH + row * 72 + 16 * kq;
                const unsigned short* fl = FTL + row * 72 + 16 * kq;
                const float* vvp = VVf + 16 * kq;
#pragma unroll
                for (int k = 0; k < 16; ++k)
                    acc += (bf2f(fh[k]) + bf2f(fl[k])) * vvp[k];
                acc += __shfl_xor(acc, 1);
                acc += __shfl_xor(acc, 2);
                if ((ln & 3) == 0) QHF[row] = acc + pv;
            }
        }
        __syncthreads();   // B1: WT, qhF ready

        // ---- P2: GEMM2 (QH = Q + F^T W via MFMA) ----
        {
            for (int ti = 0; ti < g2cnt; ++ti) {
                int T = g2base + ti, mt = T / 6, nt = T % 6;
                const unsigned short* ah = FTH + (16 * mt + l15) * 72 + 8 * lq;
                const unsigned short* al = FTL + (16 * mt + l15) * 72 + 8 * lq;
                const unsigned short* bh = WTH + (16 * nt + l15) * 72 + 8 * lq;
                const unsigned short* bl = WTL + (16 * nt + l15) * 72 + 8 * lq;
                f4v d;
                d[0] = qpre[ti][0]; d[1] = qpre[ti][1]; d[2] = qpre[ti][2]; d[3] = qpre[ti][3];
#pragma unroll
                for (int kc = 0; kc < 2; ++kc) {
                    s8v Ah = *(const s8v*)(ah + 32 * kc);
                    s8v Al = *(const s8v*)(al + 32 * kc);
                    s8v Bh = *(const s8v*)(bh + 32 * kc);
                    s8v Bl = *(const s8v*)(bl + 32 * kc);
                    d = MFMA(Ah, Bh, d);
                    d = MFMA(Ah, Bl, d);
                    d = MFMA(Al, Bh, d);
                }
                int orow = 16 * mt + 4 * lq, ocol = 16 * nt + l15;
#pragma unroll
                for (int rr = 0; rr < 4; ++rr)
                    QHf[(orow + rr) * 100 + ocol] = d[rr];
                if (mt < 4 && nt >= 4) {   // xu-block -> bf16 for Vn MFMA
                    int jc = ocol - 64;
#pragma unroll
                    for (int rr = 0; rr < 4; ++rr) {
                        float x = d[rr];
                        unsigned short h = f2bf(x);
                        XUH[(orow + rr) * 40 + jc] = h;
                        XUL[(orow + rr) * 40 + jc] = f2bf(x - bf2f(h));
                    }
                }
            }
        }
        __syncthreads();   // B2: QH ready

        // ---- P3: wave0 chol+Linv ; wave7 qh ; waves1-6 stage next FTbf ----
        if (wv == 0) {
            const int i = ln & 31;
            float a[32], rinv[32];
#pragma unroll
            for (int j4 = 0; j4 < 8; ++j4) {
                float4 v = *(const float4*)&QHf[(64 + i) * 100 + 64 + 4 * j4];
                a[4 * j4] = v.x; a[4 * j4 + 1] = v.y; a[4 * j4 + 2] = v.z; a[4 * j4 + 3] = v.w;
            }
#pragma unroll
            for (int j = 0; j < 32; ++j) {
                float dj = lanebc(a[j], j);
                float rj = rsqrtf(dj);
                rinv[j] = rj;
                a[j] *= rj;
#pragma unroll
                for (int k = j + 1; k < 32; ++k)
                    a[k] -= a[j] * lanebc(a[j], k);
            }
            float y[32];
#pragma unroll
            for (int r = 0; r < 32; ++r) {
                float acc0 = (r == i) ? 1.0f : 0.0f, acc1 = 0.0f;
#pragma unroll
                for (int j = 0; j < r; ++j) {
                    float lrj = lanebc(a[j], r);
                    if (j & 1) acc1 -= lrj * y[j]; else acc0 -= lrj * y[j];
                }
                y[r] = (acc0 + acc1) * rinv[r];
            }
            if (ln < 32) {
#pragma unroll
                for (int r = 0; r < 32; ++r) LIf[r * 36 + ln] = y[r];
            }
        } else if (wv == 7) {
            // qh[j] = qhF[j] + sum_i W[i][j] c[i] = qhF[j] + sum_i WT[j][i] c[i]
#pragma unroll
            for (int pass = 0; pass < 2; ++pass) {
                int j = pass ? (64 + (ln & 31)) : ln;
                if (pass && ln >= 32) break;
                float acc = QHF[j];
                const unsigned short* wh = WTH + j * 72;
                const unsigned short* wl = WTL + j * 72;
#pragma unroll 4
                for (int i = 0; i < 64; ++i)
                    acc += (bf2f(wh[i]) + bf2f(wl[i])) * CVf[i];
                QHf[j * 100 + 96] = acc;
            }
        } else {
            const int tau = tid - 64, kk = tau & 63, cq = tau >> 6;
#pragma unroll
            for (int q = 0; q < 4; ++q) {
                float4 v = fp4[q];
#pragma unroll
                for (int e = 0; e < 4; ++e) {
                    int col = 16 * cq + 4 * q + e;
                    float x = (e == 0) ? v.x : (e == 1) ? v.y : (e == 2) ? v.z : v.w;
                    unsigned short h = f2bf(x);
                    FTH[col * 72 + kk] = h;
                    FTL[col * 72 + kk] = f2bf(x - bf2f(h));
                }
            }
        }
        __syncthreads();   // B3: LI, qh, next-FT ready

        // ---- P4: T1T = (LI @ [Qux|qu])^T, all waves ----
        {
            const int c = tid & 63, rq = tid >> 6;
            f4v acc = {0.0f, 0.0f, 0.0f, 0.0f};
#pragma unroll
            for (int j4 = 0; j4 < 8; ++j4) {
                float4 qv = *(const float4*)&QHf[c * 100 + 64 + 4 * j4];  // Qux[j][c] via symmetry
#pragma unroll
                for (int rr = 0; rr < 4; ++rr) {
                    float4 li = *(const float4*)&LIf[(4 * rq + rr) * 36 + 4 * j4];
                    acc[rr] += dot4(li, qv);
                }
            }
            *(f4v*)&T1f[c * 36 + 4 * rq] = acc;
            if (tid < 32) {   // qu column
                float aq = 0.0f;
#pragma unroll 4
                for (int j = 0; j < 32; ++j)
                    aq += LIf[tid * 36 + j] * QHf[(64 + j) * 100 + 96];
                T1f[64 * 36 + tid] = aq;
            }
        }
        __syncthreads();   // B4: T1T ready

        // ---- P5: K = -(LI^T T1) -> KTbf + ws ; kvec ----
        {
            const int c = tid & 63, jq = tid >> 6;
            f4v acc = {0.0f, 0.0f, 0.0f, 0.0f};
#pragma unroll
            for (int i4 = 0; i4 < 8; ++i4) {
                float4 tv = *(const float4*)&T1f[c * 36 + 4 * i4];
#pragma unroll
                for (int ii = 0; ii < 4; ++ii) {
                    float4 li = *(const float4*)&LIf[(4 * i4 + ii) * 36 + 4 * jq];
                    float tvi = (ii == 0) ? tv.x : (ii == 1) ? tv.y : (ii == 2) ? tv.z : tv.w;
                    acc[0] += tvi * li.x; acc[1] += tvi * li.y;
                    acc[2] += tvi * li.z; acc[3] += tvi * li.w;
                }
            }
            float* wrow = wsK + bt * WSK_STRIDE;
#pragma unroll
            for (int jj = 0; jj < 4; ++jj) {
                float kval = -acc[jj];
                unsigned short h = f2bf(kval);
                KTH[c * 40 + 4 * jq + jj] = h;
                KTL[c * 40 + 4 * jq + jj] = f2bf(kval - bf2f(h));
                wrow[(4 * jq + jj) * 65 + c] = kval;
            }
            if (tid < 32) {   // kvec
                float aq = 0.0f;
#pragma unroll 4
                for (int i = 0; i < 32; ++i)
                    aq += LIf[i * 36 + tid] * T1f[64 * 36 + i];
                KVf[tid] = -aq;
                wsK[bt * WSK_STRIDE + tid * 65 + 64] = -aq;
            }
        }
        __syncthreads();   // B5: KTbf, kvec ready

        // ---- P6a: VRAW = Qxx + Qxu K via MFMA (16 tiles, 2/wave) ----
        {
#pragma unroll
            for (int tt = 0; tt < 2; ++tt) {
                int T = 2 * wv + tt, mt = T >> 2, nt = T & 3;
                int orow = 16 * mt + 4 * lq, ocol = 16 * nt + l15;
                f4v d;
#pragma unroll
                for (int rr = 0; rr < 4; ++rr)
                    d[rr] = QHf[(orow + rr) * 100 + ocol];
                s8v Ah = *(const s8v*)(XUH + (16 * mt + l15) * 40 + 8 * lq);
                s8v Al = *(const s8v*)(XUL + (16 * mt + l15) * 40 + 8 * lq);
                s8v Bh = *(const s8v*)(KTH + (16 * nt + l15) * 40 + 8 * lq);
                s8v Bl = *(const s8v*)(KTL + (16 * nt + l15) * 40 + 8 * lq);
                d = MFMA(Ah, Bh, d);
                d = MFMA(Ah, Bl, d);
                d = MFMA(Al, Bh, d);
#pragma unroll
                for (int rr = 0; rr < 4; ++rr)
                    VRW[(orow + rr) * 72 + ocol] = d[rr];
            }
        }
        __syncthreads();   // B6: VRAW ready

        // ---- P6b: symmetrize -> Vbf hi/lo ; vn ----
        if (tid < 256) {
            const int rg = tid >> 4, cgv = tid & 15;
            float4 m0[4], m1[4];
#pragma unroll
            for (int rr = 0; rr < 4; ++rr) {
                m0[rr] = *(const float4*)&VRW[(4 * rg + rr) * 72 + 4 * cgv];
                m1[rr] = *(const float4*)&VRW[(4 * cgv + rr) * 72 + 4 * rg];
            }
#pragma unroll
            for (int rr = 0; rr < 4; ++rr) {
                float s0 = 0.5f * (m0[rr].x + m1[0][rr < 1 ? 0 : rr]);   // placeholder (replaced below)
                (void)s0;
            }
            // explicit symmetrize: s[rr][cc] = 0.5*(m0[rr][cc] + m1[cc][rr])
#pragma unroll
            for (int rr = 0; rr < 4; ++rr) {
                float s[4];
                s[0] = 0.5f * (m0[rr].x + ((float*)&m1[0])[rr]);
                s[1] = 0.5f * (m0[rr].y + ((float*)&m1[1])[rr]);
                s[2] = 0.5f * (m0[rr].z + ((float*)&m1[2])[rr]);
                s[3] = 0.5f * (m0[rr].w + ((float*)&m1[3])[rr]);
                unsigned short h[4], lo[4];
#pragma unroll
                for (int cc = 0; cc < 4; ++cc) {
                    h[cc]  = f2bf(s[cc]);
                    lo[cc] = f2bf(s[cc] - bf2f(h[cc]));
                }
                ushort4 hv = make_ushort4(h[0], h[1], h[2], h[3]);
                ushort4 lv = make_ushort4(lo[0], lo[1], lo[2], lo[3]);
                *(ushort4*)&VBH[(4 * rg + rr) * 72 + 4 * cgv] = hv;
                *(ushort4*)&VBL[(4 * rg + rr) * 72 + 4 * cgv] = lv;
            }
        } else if (tid < 320) {
            const int r = tid & 63;
            float acc = QHf[r * 100 + 96];
#pragma unroll
            for (int j4 = 0; j4 < 8; ++j4) {
                float4 qv = *(const float4*)&QHf[r * 100 + 64 + 4 * j4];
                float4 kv = *(const float4*)&KVf[4 * j4];
                acc += dot4(qv, kv);
            }
            VVf[r] = acc;
        }
        __syncthreads();   // B7: V, v ready for next step
    }

    // ================= forward rollout (as R2) =================
    float* sm = (float*)smb;
    {
        const size_t bt0 = (size_t)b * TT;
#pragma unroll
        for (int it = 0; it < 3; ++it) {
            int q = tid + 512 * it, row = q / 24, g = q % 24;
            const float* src = (g < 16) ? (A + (bt0 * 64 + row) * 64 + 4 * g)
                                        : (B + (bt0 * 64 + row) * 32 + 4 * (g - 16));
            *(float4*)&sm[AB0 + row * 100 + 4 * g] = *(const float4*)src;
        }
#pragma unroll
        for (int i = 0; i < 5; ++i) {
            int idx = tid + 512 * i;
            if (idx < 2080) {
                int j = idx / 65, c = idx - 65 * j;
                sm[KF0 + j * 68 + c] = wsK[bt0 * WSK_STRIDE + idx];
            }
        }
        if (tid < 64) sm[XB0 + tid] = xinit[b * 64 + tid];
    }
    __syncthreads();

    for (int t = 0; t < TT; ++t) {
        const size_t bt  = (size_t)b * TT + t;
        const size_t btn = (size_t)b * TT + ((t < TT - 1) ? (t + 1) : t);
        const int cur = t & 1;
        const int abC = cur ? AB1 : AB0, abN = cur ? AB0 : AB1;
        const int kfC = cur ? KF1 : KF0, kfN = cur ? KF0 : KF1;
        const int xbC = cur ? XB1 : XB0, xbN = cur ? XB0 : XB1;

        float4 abpre[6];
        float kpre[9];
        float cpre = 0.0f;
        if (tid >= 256) {
            const int t2 = tid - 256;
#pragma unroll
            for (int it = 0; it < 6; ++it) {
                int q = t2 + 256 * it, row = q / 24, g = q % 24;
                const float* src = (g < 16) ? (A + (btn * 64 + row) * 64 + 4 * g)
                                            : (B + (btn * 64 + row) * 32 + 4 * (g - 16));
                abpre[it] = *(const float4*)src;
            }
#pragma unroll
            for (int i = 0; i < 9; ++i) {
                int idx = t2 + 256 * i;
                kpre[i] = (idx < 2080) ? wsK[btn * WSK_STRIDE + idx] : 0.0f;
            }
            cpre = c1[bt * 64 + ((tid - 256) >> 2)];
        }

        if (tid < 256) {
            const int j = tid >> 3, q = tid & 7;
            float4 k0 = *(const float4*)&sm[kfC + j * 68 + 8 * q];
            float4 k1 = *(const float4*)&sm[kfC + j * 68 + 8 * q + 4];
            float4 x0 = *(const float4*)&sm[xbC + 8 * q];
            float4 x1 = *(const float4*)&sm[xbC + 8 * q + 4];
            float pa = dot4(k0, x0) + dot4(k1, x1);
            pa += __shfl_xor(pa, 1);
            pa += __shfl_xor(pa, 2);
            pa += __shfl_xor(pa, 4);
            if (q == 0) {
                float u = pa + sm[kfC + j * 68 + 64];
                sm[UBO + j] = u;
                out[bt * 96 + 64 + j] = u;
            }
        } else {
            const int r = (tid - 256) >> 2, q = tid & 3;
            float pa = 0.0f;
#pragma unroll
            for (int e4 = 0; e4 < 4; ++e4) {
                float4 av = *(const float4*)&sm[abC + r * 100 + 16 * q + 4 * e4];
                float4 xv = *(const float4*)&sm[xbC + 16 * q + 4 * e4];
                pa += dot4(av, xv);
            }
            pa += __shfl_xor(pa, 1);
            pa += __shfl_xor(pa, 2);
            if (q == 0) sm[AXO + r] = pa + cpre;
            if (q == 1) out[bt * 96 + r] = sm[xbC + r];
        }
        __syncthreads();

        if (tid < 256) {
            const int r = tid >> 2, q = tid & 3;
            float4 b0 = *(const float4*)&sm[abC + r * 100 + 64 + 8 * q];
            float4 b1 = *(const float4*)&sm[abC + r * 100 + 64 + 8 * q + 4];
            float4 u0 = *(const float4*)&sm[UBO + 8 * q];
            float4 u1 = *(const float4*)&sm[UBO + 8 * q + 4];
            float pa = dot4(b0, u0) + dot4(b1, u1);
            pa += __shfl_xor(pa, 1);
            pa += __shfl_xor(pa, 2);
            if (q == 0) sm[xbN + r] = sm[AXO + r] + pa;
        } else {
            const int t2 = tid - 256;
#pragma unroll
            for (int it = 0; it < 6; ++it) {
                int q = t2 + 256 * it, row = q / 24, g = q % 24;
                *(float4*)&sm[abN + row * 100 + 4 * g] = abpre[it];
            }
#pragma unroll
            for (int i = 0; i < 9; ++i) {
                int idx = t2 + 256 * i;
                if (idx < 2080) {
                    int j = idx / 65, c = idx - 65 * j;
                    sm[kfN + j * 68 + c] = kpre[i];
                }
            }
        }
        __syncthreads();
    }
}

extern "C" void kernel_launch(void* const* d_in, const int* in_sizes, int n_in,
                              void* d_out, int out_size, void* d_ws, size_t ws_size,
                              hipStream_t stream) {
    (void)in_sizes; (void)n_in; (void)out_size;
    const float* Q  = (const float*)d_in[0];
    const float* p  = (const float*)d_in[1];
    const float* A  = (const float*)d_in[2];
    const float* B  = (const float*)d_in[3];
    const float* c1 = (const float*)d_in[4];
    const float* xi = (const float*)d_in[5];
    if (ws_size < (size_t)NB * TT * WSK_STRIDE * sizeof(float)) return;
    lqr_kernel<<<NB, 512, 0, stream>>>(Q, p, A, B, c1, xi, (float*)d_out, (float*)d_ws);
}

// Round 4
// 9074.291 us; speedup vs baseline: 2.8206x; 1.1762x over previous
//
#include <hip/hip_runtime.h>
#include <math.h>

#define TT 512
#define NB 16

// ---------------- LDS byte offsets (backward) ----------------
#define QH_B   0        // QH  [96][100] f32 (col 96 = qh)
#define LI_B   38400    // LI  [32][36]  f32
#define T1_B   43008    // T1T [65][36]  f32  (row 64 = qu-solve)
#define VBH_B  52368    // Vbf-hi [64][72] us
#define VBL_B  61584    // Vbf-lo
#define FTH_B  70800    // FTbf-hi [96][72] us   FT[c][k] = F[k][c]
#define FTL_B  84624
#define WTH_B  98448    // WTbf-hi [96][72] us   WT[c][i] = W[i][c]
#define WTL_B  112272
#define VR_B   98448    // VRAW [64][72] f32 (aliases WT region, P6 only)
#define XUH_B  126096   // QXUbf-hi [64][40] us  XU[xrow][ucol]
#define XUL_B  131216
#define KTH_B  136336   // KTbf-hi [64][40] us   KT[c][j] = K[j][c]
#define KTL_B  141456
#define QHF_B  146576   // qhF [96] f32
#define VV_B   146960   // v [64] f32
#define CV_B   147216   // c [64] f32
#define KV_B   147472   // k [32] f32
#define SMB    147600

// ---------------- forward overlay (float offsets) ----------------
#define AB0 0
#define AB1 6400
#define KF0 12800
#define KF1 14976
#define XB0 17152
#define XB1 17216
#define UBO 17280
#define AXO 17312

#define WSK_STRIDE 2080   // per (b,t): rows j: [j*65 + c], col 64 = k

typedef __attribute__((ext_vector_type(8))) short s8v;
typedef __attribute__((ext_vector_type(4))) float f4v;

__device__ __forceinline__ float lanebc(float x, int lane) {
    return __int_as_float(__builtin_amdgcn_readlane(__float_as_int(x), lane));
}
__device__ __forceinline__ float dot4(float4 a, float4 b) {
    return a.x * b.x + a.y * b.y + a.z * b.z + a.w * b.w;
}
__device__ __forceinline__ unsigned short f2bf(float x) {
    unsigned int u = __float_as_uint(x);
    u += 0x7FFFu + ((u >> 16) & 1u);           // RNE
    return (unsigned short)(u >> 16);
}
__device__ __forceinline__ float bf2f(unsigned short h) {
    return __uint_as_float(((unsigned int)h) << 16);
}
// lower-triangular 16x16 tile enumeration: T=0..20 -> (mt,nt), nt<=mt
__device__ __forceinline__ void tileMN(int T, int& mt, int& nt) {
    mt = (T >= 15) ? 5 : (T >= 10) ? 4 : (T >= 6) ? 3 : (T >= 3) ? 2 : (T >= 1) ? 1 : 0;
    nt = T - mt * (mt + 1) / 2;
}
#define MFMA(a,b,c) __builtin_amdgcn_mfma_f32_16x16x32_bf16((a),(b),(c),0,0,0)

__launch_bounds__(512, 2)
__global__ void lqr_kernel(const float* __restrict__ Q, const float* __restrict__ P,
                           const float* __restrict__ A, const float* __restrict__ B,
                           const float* __restrict__ c1, const float* __restrict__ xinit,
                           float* __restrict__ out, float* __restrict__ ws)
{
    __shared__ __align__(16) unsigned char smb[SMB];
    float*          QHf = (float*)(smb + QH_B);
    float*          LIf = (float*)(smb + LI_B);
    float*          T1f = (float*)(smb + T1_B);
    unsigned short* VBH = (unsigned short*)(smb + VBH_B);
    unsigned short* VBL = (unsigned short*)(smb + VBL_B);
    unsigned short* FTH = (unsigned short*)(smb + FTH_B);
    unsigned short* FTL = (unsigned short*)(smb + FTL_B);
    unsigned short* WTH = (unsigned short*)(smb + WTH_B);
    unsigned short* WTL = (unsigned short*)(smb + WTL_B);
    float*          VRW = (float*)(smb + VR_B);
    unsigned short* XUH = (unsigned short*)(smb + XUH_B);
    unsigned short* XUL = (unsigned short*)(smb + XUL_B);
    unsigned short* KTH = (unsigned short*)(smb + KTH_B);
    unsigned short* KTL = (unsigned short*)(smb + KTL_B);
    float*          QHF = (float*)(smb + QHF_B);
    float*          VVf = (float*)(smb + VV_B);
    float*          CVf = (float*)(smb + CV_B);
    float*          KVf = (float*)(smb + KV_B);

    const int tid = threadIdx.x;
    const int b   = blockIdx.x;
    const int wv  = tid >> 6;
    const int ln  = tid & 63;
    const int l15 = ln & 15;
    const int lq  = ln >> 4;
    float* wsK = ws;

    const int qcnt = (wv < 5) ? 3 : 2;      // lower tiles per wave
    const int qr = ln >> 2, qc4 = ln & 3;   // Q-stage lane mapping

    // ---- prologue: issue Q loads for t=511 immediately ----
    float4 qreg[3];
    {
        const float* Qg = Q + ((size_t)b * TT + (TT - 1)) * 9216;
        for (int tt = 0; tt < qcnt; ++tt) {
            int T = wv + 8 * tt, mt, nt; tileMN(T, mt, nt);
            qreg[tt] = *(const float4*)&Qg[(16 * mt + qr) * 96 + 16 * nt + 4 * qc4];
        }
    }

    // ---------------- init: Vbf=0, v=0, stage FTbf for t=511 ----------------
    if (tid < 384) {
        const size_t bt = (size_t)b * TT + (TT - 1);
        const int kk = tid & 63, cq = tid >> 6;
#pragma unroll
        for (int q = 0; q < 4; ++q) {
            const float* src = (cq < 4) ? (A + (bt * 64 + kk) * 64 + 16 * cq + 4 * q)
                                        : (B + (bt * 64 + kk) * 32 + 16 * (cq - 4) + 4 * q);
            float4 v = *(const float4*)src;
#pragma unroll
            for (int e = 0; e < 4; ++e) {
                int col = 16 * cq + 4 * q + e;
                float x = (e == 0) ? v.x : (e == 1) ? v.y : (e == 2) ? v.z : v.w;
                unsigned short h = f2bf(x);
                FTH[col * 72 + kk] = h;
                FTL[col * 72 + kk] = f2bf(x - bf2f(h));
            }
        }
    } else {
        float* vb = (float*)VBH;   // zero Vbf hi+lo (4608 floats contiguous)
        for (int i = tid - 384; i < 4608; i += 128) vb[i] = 0.0f;
        if (tid >= 448) VVf[tid - 448] = 0.0f;
    }
    __syncthreads();

    // ================= backward Riccati recursion =================
    for (int t = TT - 1; t >= 0; --t) {
        const size_t bt  = (size_t)b * TT + t;
        const size_t btp = (size_t)b * TT + ((t > 0) ? (t - 1) : 0);

        // ---- P1-start: commit prefetched Q_t tiles to QHf staging ----
        for (int tt = 0; tt < qcnt; ++tt) {
            int T = wv + 8 * tt, mt, nt; tileMN(T, mt, nt);
            *(float4*)&QHf[(16 * mt + qr) * 100 + 16 * nt + 4 * qc4] = qreg[tt];
        }
        // issue Q loads for next step (full-step latency window)
        {
            const float* Qg = Q + btp * 9216;
            for (int tt = 0; tt < qcnt; ++tt) {
                int T = wv + 8 * tt, mt, nt; tileMN(T, mt, nt);
                qreg[tt] = *(const float4*)&Qg[(16 * mt + qr) * 96 + 16 * nt + 4 * qc4];
            }
        }
        // A/B prefetch for next-step FT staging (consumed at P3)
        float4 fp4[4];
        if (wv >= 1 && wv <= 6) {
            const int tau = tid - 64, kk = tau & 63, cq = tau >> 6;
#pragma unroll
            for (int q = 0; q < 4; ++q) {
                const float* src = (cq < 4) ? (A + (btp * 64 + kk) * 64 + 16 * cq + 4 * q)
                                            : (B + (btp * 64 + kk) * 32 + 16 * (cq - 4) + 4 * q);
                fp4[q] = *(const float4*)src;
            }
        }
        if (wv == 7 && ln < 16)
            *(float4*)&CVf[4 * ln] = *(const float4*)&c1[bt * 64 + 4 * ln];
        float pv = 0.0f;
        if (ln < 48 && (ln & 3) == 0) pv = P[bt * 96 + 12 * wv + (ln >> 2)];

        // ---- P1: GEMM1 (WT = (VF)^T via MFMA) + qhF = p + F^T v ----
        {
#pragma unroll
            for (int tt = 0; tt < 3; ++tt) {
                int T = wv * 3 + tt, mt = T >> 2, nt = T & 3;
                const unsigned short* ah = FTH + (16 * mt + l15) * 72 + 8 * lq;
                const unsigned short* al = FTL + (16 * mt + l15) * 72 + 8 * lq;
                const unsigned short* bh = VBH + (16 * nt + l15) * 72 + 8 * lq;
                const unsigned short* bl = VBL + (16 * nt + l15) * 72 + 8 * lq;
                f4v d = {0.0f, 0.0f, 0.0f, 0.0f};
#pragma unroll
                for (int kc = 0; kc < 2; ++kc) {
                    s8v Ah = *(const s8v*)(ah + 32 * kc);
                    s8v Al = *(const s8v*)(al + 32 * kc);
                    s8v Bh = *(const s8v*)(bh + 32 * kc);
                    s8v Bl = *(const s8v*)(bl + 32 * kc);
                    d = MFMA(Ah, Bh, d);
                    d = MFMA(Ah, Bl, d);
                    d = MFMA(Al, Bh, d);
                }
                int orow = 16 * mt + 4 * lq, ocol = 16 * nt + l15;
#pragma unroll
                for (int rr = 0; rr < 4; ++rr) {
                    float x = d[rr];
                    unsigned short h = f2bf(x);
                    WTH[(orow + rr) * 72 + ocol] = h;
                    WTL[(orow + rr) * 72 + ocol] = f2bf(x - bf2f(h));
                }
            }
            // qhF: row = 12*wv + (ln>>2), k-quarter = ln&3
            if (ln < 48) {
                int row = 12 * wv + (ln >> 2), kq = ln & 3;
                float acc = 0.0f;
                const unsigned short* fh = FTH + row * 72 + 16 * kq;
                const unsigned short* fl = FTL + row * 72 + 16 * kq;
                const float* vvp = VVf + 16 * kq;
#pragma unroll
                for (int k = 0; k < 16; ++k)
                    acc += (bf2f(fh[k]) + bf2f(fl[k])) * vvp[k];
                acc += __shfl_xor(acc, 1);
                acc += __shfl_xor(acc, 2);
                if ((ln & 3) == 0) QHF[row] = acc + pv;
            }
        }
        __syncthreads();   // B1: WT, qhF, Q-stage ready

        // ---- P2: QH lower tiles = Qstage + F^T W via MFMA; mirror; XU pack ----
        {
            for (int tt = 0; tt < qcnt; ++tt) {
                int T = wv + 8 * tt, mt, nt; tileMN(T, mt, nt);
                int orow = 16 * mt + 4 * lq, ocol = 16 * nt + l15;
                const unsigned short* ah = FTH + (16 * mt + l15) * 72 + 8 * lq;
                const unsigned short* al = FTL + (16 * mt + l15) * 72 + 8 * lq;
                const unsigned short* bh = WTH + (16 * nt + l15) * 72 + 8 * lq;
                const unsigned short* bl = WTL + (16 * nt + l15) * 72 + 8 * lq;
                f4v d;
#pragma unroll
                for (int rr = 0; rr < 4; ++rr)
                    d[rr] = QHf[(orow + rr) * 100 + ocol];    // C-init = staged Q
#pragma unroll
                for (int kc = 0; kc < 2; ++kc) {
                    s8v Ah = *(const s8v*)(ah + 32 * kc);
                    s8v Al = *(const s8v*)(al + 32 * kc);
                    s8v Bh = *(const s8v*)(bh + 32 * kc);
                    s8v Bl = *(const s8v*)(bl + 32 * kc);
                    d = MFMA(Ah, Bh, d);
                    d = MFMA(Ah, Bl, d);
                    d = MFMA(Al, Bh, d);
                }
#pragma unroll
                for (int rr = 0; rr < 4; ++rr)
                    QHf[(orow + rr) * 100 + ocol] = d[rr];
                if (mt > nt) {   // mirror to upper triangle
#pragma unroll
                    for (int rr = 0; rr < 4; ++rr)
                        QHf[ocol * 100 + orow + rr] = d[rr];
                }
                if (mt >= 4 && nt < 4) {   // ux tile -> XU (Qxu[x][u]) bf16 pack
#pragma unroll
                    for (int rr = 0; rr < 4; ++rr) {
                        float x = d[rr];
                        unsigned short h = f2bf(x);
                        XUH[ocol * 40 + (orow + rr - 64)] = h;
                        XUL[ocol * 40 + (orow + rr - 64)] = f2bf(x - bf2f(h));
                    }
                }
            }
        }
        __syncthreads();   // B2: QH (full, mirrored) ready

        // ---- P3: wave0 chol+Linv ; wave7 qh ; waves1-6 stage next FTbf ----
        if (wv == 0) {
            const int i = ln & 31;
            float a[32], rinv[32];
#pragma unroll
            for (int j4 = 0; j4 < 8; ++j4) {
                float4 v = *(const float4*)&QHf[(64 + i) * 100 + 64 + 4 * j4];
                a[4 * j4] = v.x; a[4 * j4 + 1] = v.y; a[4 * j4 + 2] = v.z; a[4 * j4 + 3] = v.w;
            }
#pragma unroll
            for (int j = 0; j < 32; ++j) {
                float dj = lanebc(a[j], j);
                float rj = rsqrtf(dj);
                rinv[j] = rj;
                a[j] *= rj;
#pragma unroll
                for (int k = j + 1; k < 32; ++k)
                    a[k] -= a[j] * lanebc(a[j], k);
            }
            float y[32];
#pragma unroll
            for (int r = 0; r < 32; ++r) {
                float acc0 = (r == i) ? 1.0f : 0.0f, acc1 = 0.0f;
#pragma unroll
                for (int j = 0; j < r; ++j) {
                    float lrj = lanebc(a[j], r);
                    if (j & 1) acc1 -= lrj * y[j]; else acc0 -= lrj * y[j];
                }
                y[r] = (acc0 + acc1) * rinv[r];
            }
            if (ln < 32) {
#pragma unroll
                for (int r = 0; r < 32; ++r) LIf[r * 36 + ln] = y[r];
            }
        } else if (wv == 7) {
            // qh[j] = qhF[j] + sum_i WT[j][i] c[i]
#pragma unroll
            for (int pass = 0; pass < 2; ++pass) {
                int j = pass ? (64 + (ln & 31)) : ln;
                if (pass && ln >= 32) break;
                float acc = QHF[j];
                const unsigned short* wh = WTH + j * 72;
                const unsigned short* wl = WTL + j * 72;
#pragma unroll 4
                for (int i = 0; i < 64; ++i)
                    acc += (bf2f(wh[i]) + bf2f(wl[i])) * CVf[i];
                QHf[j * 100 + 96] = acc;
            }
        } else {
            const int tau = tid - 64, kk = tau & 63, cq = tau >> 6;
#pragma unroll
            for (int q = 0; q < 4; ++q) {
                float4 v = fp4[q];
#pragma unroll
                for (int e = 0; e < 4; ++e) {
                    int col = 16 * cq + 4 * q + e;
                    float x = (e == 0) ? v.x : (e == 1) ? v.y : (e == 2) ? v.z : v.w;
                    unsigned short h = f2bf(x);
                    FTH[col * 72 + kk] = h;
                    FTL[col * 72 + kk] = f2bf(x - bf2f(h));
                }
            }
        }
        __syncthreads();   // B3: LI, qh, next-FT ready

        // ---- P4: T1T = (LI @ [Qux|qu])^T, all waves ----
        {
            const int c = tid & 63, rq = tid >> 6;
            f4v acc = {0.0f, 0.0f, 0.0f, 0.0f};
#pragma unroll
            for (int j4 = 0; j4 < 8; ++j4) {
                float4 qv = *(const float4*)&QHf[c * 100 + 64 + 4 * j4];  // Qux[j][c] via symmetry
#pragma unroll
                for (int rr = 0; rr < 4; ++rr) {
                    float4 li = *(const float4*)&LIf[(4 * rq + rr) * 36 + 4 * j4];
                    acc[rr] += dot4(li, qv);
                }
            }
            *(f4v*)&T1f[c * 36 + 4 * rq] = acc;
            if (tid < 32) {   // qu column
                float aq = 0.0f;
#pragma unroll 4
                for (int j = 0; j < 32; ++j)
                    aq += LIf[tid * 36 + j] * QHf[(64 + j) * 100 + 96];
                T1f[64 * 36 + tid] = aq;
            }
        }
        __syncthreads();   // B4: T1T ready

        // ---- P5: K = -(LI^T T1) -> KTbf + ws ; kvec ----
        {
            const int c = tid & 63, jq = tid >> 6;
            f4v acc = {0.0f, 0.0f, 0.0f, 0.0f};
#pragma unroll
            for (int i4 = 0; i4 < 8; ++i4) {
                float4 tv = *(const float4*)&T1f[c * 36 + 4 * i4];
#pragma unroll
                for (int ii = 0; ii < 4; ++ii) {
                    float4 li = *(const float4*)&LIf[(4 * i4 + ii) * 36 + 4 * jq];
                    float tvi = (ii == 0) ? tv.x : (ii == 1) ? tv.y : (ii == 2) ? tv.z : tv.w;
                    acc[0] += tvi * li.x; acc[1] += tvi * li.y;
                    acc[2] += tvi * li.z; acc[3] += tvi * li.w;
                }
            }
            float* wrow = wsK + bt * WSK_STRIDE;
#pragma unroll
            for (int jj = 0; jj < 4; ++jj) {
                float kval = -acc[jj];
                unsigned short h = f2bf(kval);
                KTH[c * 40 + 4 * jq + jj] = h;
                KTL[c * 40 + 4 * jq + jj] = f2bf(kval - bf2f(h));
                wrow[(4 * jq + jj) * 65 + c] = kval;
            }
            if (tid < 32) {   // kvec
                float aq = 0.0f;
#pragma unroll 4
                for (int i = 0; i < 32; ++i)
                    aq += LIf[i * 36 + tid] * T1f[64 * 36 + i];
                KVf[tid] = -aq;
                wsK[bt * WSK_STRIDE + tid * 65 + 64] = -aq;
            }
        }
        __syncthreads();   // B5: KTbf, kvec ready

        // ---- P6a: VRAW = Qxx + Qxu K via MFMA (16 tiles, 2/wave) ----
        {
#pragma unroll
            for (int tt = 0; tt < 2; ++tt) {
                int T = 2 * wv + tt, mt = T >> 2, nt = T & 3;
                int orow = 16 * mt + 4 * lq, ocol = 16 * nt + l15;
                f4v d;
#pragma unroll
                for (int rr = 0; rr < 4; ++rr)
                    d[rr] = QHf[(orow + rr) * 100 + ocol];
                s8v Ah = *(const s8v*)(XUH + (16 * mt + l15) * 40 + 8 * lq);
                s8v Al = *(const s8v*)(XUL + (16 * mt + l15) * 40 + 8 * lq);
                s8v Bh = *(const s8v*)(KTH + (16 * nt + l15) * 40 + 8 * lq);
                s8v Bl = *(const s8v*)(KTL + (16 * nt + l15) * 40 + 8 * lq);
                d = MFMA(Ah, Bh, d);
                d = MFMA(Ah, Bl, d);
                d = MFMA(Al, Bh, d);
#pragma unroll
                for (int rr = 0; rr < 4; ++rr)
                    VRW[(orow + rr) * 72 + ocol] = d[rr];
            }
        }
        __syncthreads();   // B6: VRAW ready

        // ---- P6b: symmetrize -> Vbf hi/lo ; vn ----
        if (tid < 256) {
            const int rg = tid >> 4, cgv = tid & 15;
            float4 m0[4], m1[4];
#pragma unroll
            for (int rr = 0; rr < 4; ++rr) {
                m0[rr] = *(const float4*)&VRW[(4 * rg + rr) * 72 + 4 * cgv];
                m1[rr] = *(const float4*)&VRW[(4 * cgv + rr) * 72 + 4 * rg];
            }
#pragma unroll
            for (int rr = 0; rr < 4; ++rr) {
                float s[4];
                s[0] = 0.5f * (m0[rr].x + ((float*)&m1[0])[rr]);
                s[1] = 0.5f * (m0[rr].y + ((float*)&m1[1])[rr]);
                s[2] = 0.5f * (m0[rr].z + ((float*)&m1[2])[rr]);
                s[3] = 0.5f * (m0[rr].w + ((float*)&m1[3])[rr]);
                unsigned short h[4], lo[4];
#pragma unroll
                for (int cc = 0; cc < 4; ++cc) {
                    h[cc]  = f2bf(s[cc]);
                    lo[cc] = f2bf(s[cc] - bf2f(h[cc]));
                }
                ushort4 hv = make_ushort4(h[0], h[1], h[2], h[3]);
                ushort4 lv = make_ushort4(lo[0], lo[1], lo[2], lo[3]);
                *(ushort4*)&VBH[(4 * rg + rr) * 72 + 4 * cgv] = hv;
                *(ushort4*)&VBL[(4 * rg + rr) * 72 + 4 * cgv] = lv;
            }
        } else if (tid < 320) {
            const int r = tid & 63;
            float acc = QHf[r * 100 + 96];
#pragma unroll
            for (int j4 = 0; j4 < 8; ++j4) {
                float4 qv = *(const float4*)&QHf[r * 100 + 64 + 4 * j4];
                float4 kv = *(const float4*)&KVf[4 * j4];
                acc += dot4(qv, kv);
            }
            VVf[r] = acc;
        }
        __syncthreads();   // B7: V, v ready for next step
    }

    // ================= forward rollout (as R3) =================
    float* sm = (float*)smb;
    {
        const size_t bt0 = (size_t)b * TT;
#pragma unroll
        for (int it = 0; it < 3; ++it) {
            int q = tid + 512 * it, row = q / 24, g = q % 24;
            const float* src = (g < 16) ? (A + (bt0 * 64 + row) * 64 + 4 * g)
                                        : (B + (bt0 * 64 + row) * 32 + 4 * (g - 16));
            *(float4*)&sm[AB0 + row * 100 + 4 * g] = *(const float4*)src;
        }
#pragma unroll
        for (int i = 0; i < 5; ++i) {
            int idx = tid + 512 * i;
            if (idx < 2080) {
                int j = idx / 65, c = idx - 65 * j;
                sm[KF0 + j * 68 + c] = wsK[bt0 * WSK_STRIDE + idx];
            }
        }
        if (tid < 64) sm[XB0 + tid] = xinit[b * 64 + tid];
    }
    __syncthreads();

    for (int t = 0; t < TT; ++t) {
        const size_t bt  = (size_t)b * TT + t;
        const size_t btn = (size_t)b * TT + ((t < TT - 1) ? (t + 1) : t);
        const int cur = t & 1;
        const int abC = cur ? AB1 : AB0, abN = cur ? AB0 : AB1;
        const int kfC = cur ? KF1 : KF0, kfN = cur ? KF0 : KF1;
        const int xbC = cur ? XB1 : XB0, xbN = cur ? XB0 : XB1;

        float4 abpre[6];
        float kpre[9];
        float cpre = 0.0f;
        if (tid >= 256) {
            const int t2 = tid - 256;
#pragma unroll
            for (int it = 0; it < 6; ++it) {
                int q = t2 + 256 * it, row = q / 24, g = q % 24;
                const float* src = (g < 16) ? (A + (btn * 64 + row) * 64 + 4 * g)
                                            : (B + (btn * 64 + row) * 32 + 4 * (g - 16));
                abpre[it] = *(const float4*)src;
            }
#pragma unroll
            for (int i = 0; i < 9; ++i) {
                int idx = t2 + 256 * i;
                kpre[i] = (idx < 2080) ? wsK[btn * WSK_STRIDE + idx] : 0.0f;
            }
            cpre = c1[bt * 64 + ((tid - 256) >> 2)];
        }

        if (tid < 256) {
            const int j = tid >> 3, q = tid & 7;
            float4 k0 = *(const float4*)&sm[kfC + j * 68 + 8 * q];
            float4 k1 = *(const float4*)&sm[kfC + j * 68 + 8 * q + 4];
            float4 x0 = *(const float4*)&sm[xbC + 8 * q];
            float4 x1 = *(const float4*)&sm[xbC + 8 * q + 4];
            float pa = dot4(k0, x0) + dot4(k1, x1);
            pa += __shfl_xor(pa, 1);
            pa += __shfl_xor(pa, 2);
            pa += __shfl_xor(pa, 4);
            if (q == 0) {
                float u = pa + sm[kfC + j * 68 + 64];
                sm[UBO + j] = u;
                out[bt * 96 + 64 + j] = u;
            }
        } else {
            const int r = (tid - 256) >> 2, q = tid & 3;
            float pa = 0.0f;
#pragma unroll
            for (int e4 = 0; e4 < 4; ++e4) {
                float4 av = *(const float4*)&sm[abC + r * 100 + 16 * q + 4 * e4];
                float4 xv = *(const float4*)&sm[xbC + 16 * q + 4 * e4];
                pa += dot4(av, xv);
            }
            pa += __shfl_xor(pa, 1);
            pa += __shfl_xor(pa, 2);
            if (q == 0) sm[AXO + r] = pa + cpre;
            if (q == 1) out[bt * 96 + r] = sm[xbC + r];
        }
        __syncthreads();

        if (tid < 256) {
            const int r = tid >> 2, q = tid & 3;
            float4 b0 = *(const float4*)&sm[abC + r * 100 + 64 + 8 * q];
            float4 b1 = *(const float4*)&sm[abC + r * 100 + 64 + 8 * q + 4];
            float4 u0 = *(const float4*)&sm[UBO + 8 * q];
            float4 u1 = *(const float4*)&sm[UBO + 8 * q + 4];
            float pa = dot4(b0, u0) + dot4(b1, u1);
            pa += __shfl_xor(pa, 1);
            pa += __shfl_xor(pa, 2);
            if (q == 0) sm[xbN + r] = sm[AXO + r] + pa;
        } else {
            const int t2 = tid - 256;
#pragma unroll
            for (int it = 0; it < 6; ++it) {
                int q = t2 + 256 * it, row = q / 24, g = q % 24;
                *(float4*)&sm[abN + row * 100 + 4 * g] = abpre[it];
            }
#pragma unroll
            for (int i = 0; i < 9; ++i) {
                int idx = t2 + 256 * i;
                if (idx < 2080) {
                    int j = idx / 65, c = idx - 65 * j;
                    sm[kfN + j * 68 + c] = kpre[i];
                }
            }
        }
        __syncthreads();
    }
}

extern "C" void kernel_launch(void* const* d_in, const int* in_sizes, int n_in,
                              void* d_out, int out_size, void* d_ws, size_t ws_size,
                              hipStream_t stream) {
    (void)in_sizes; (void)n_in; (void)out_size;
    const float* Q  = (const float*)d_in[0];
    const float* p  = (const float*)d_in[1];
    const float* A  = (const float*)d_in[2];
    const float* B  = (const float*)d_in[3];
    const float* c1 = (const float*)d_in[4];
    const float* xi = (const float*)d_in[5];
    if (ws_size < (size_t)NB * TT * WSK_STRIDE * sizeof(float)) return;
    lqr_kernel<<<NB, 512, 0, stream>>>(Q, p, A, B, c1, xi, (float*)d_out, (float*)d_ws);
}